// Round 8
// baseline (4066.253 us; speedup 1.0000x reference)
//
#include <hip/hip_runtime.h>
#include <math.h>

typedef _Float16 half8 __attribute__((ext_vector_type(8)));
typedef float float4v __attribute__((ext_vector_type(4)));

constexpr int Lc   = 2048;  // L_IN
constexpr int DECc = 64;    // DEC_LEN
constexpr int Hc   = 128;   // H
constexpr int EMBc = 16;    // EMB
constexpr int INc  = 18;    // IN_SIZE
constexpr int NBc  = 4;     // batches per block
constexpr int NTc  = 512;   // 8 waves
constexpr int KT   = 5;     // k-tiles of 32 (z padded to 160)
constexpr int CARD = 200;

__device__ __forceinline__ float sigm(float x) {
    return 1.0f / (1.0f + exp2f(-1.44269504f * x));
}
__device__ __forceinline__ float tanh_(float x) {
    return 2.0f / (1.0f + exp2f(-2.88539008f * x)) - 1.0f;
}
__device__ __forceinline__ float softplus_(float x) {
    return 0.69314718f * log2f(1.0f + exp2f(1.44269504f * x));
}

// z LDS layout = B-fragment order for mfma_f32_16x16x32_f16 (verified R4-R7):
// frag kt: lane l holds halves [l*8..l*8+8) = B[k = kt*32 + (l>>4)*8 + j][n = l&15]
__device__ __forceinline__ int zslot(int k, int b) {
    return (k >> 5) * 512 + (b + 16 * ((k & 31) >> 3)) * 8 + (k & 7);
}

__global__ __launch_bounds__(NTc, 2) void rnnar_kernel(
    const int*   __restrict__ cat_in,  const float* __restrict__ cont_in,
    const float* __restrict__ X_in,    const int*   __restrict__ cat_out,
    const float* __restrict__ cont_out,const float* __restrict__ emb_table,
    const float* __restrict__ cont_w,
    const float* __restrict__ Wih_e, const float* __restrict__ Whh_e, const float* __restrict__ b_e,
    const float* __restrict__ Wih_d, const float* __restrict__ Whh_d, const float* __restrict__ b_d,
    const float* __restrict__ Wm, const float* __restrict__ bm,
    const float* __restrict__ Ws, const float* __restrict__ bs,
    const float* __restrict__ Wv, const float* __restrict__ bv,
    float* __restrict__ out)
{
    // total static LDS ~63.6 KB (fits 64 KB workgroup limit)
    __shared__ _Float16      z_lds[2][KT * 512];   // 10 KB  double-buffered B-frags
    __shared__ _Float16      emb_lds[CARD * EMBc]; // 6.4 KB embedding table (f16)
    __shared__ _Float16      xs0[NBc * Lc];        // 16 KB  cont_in * w00  (f16)
    __shared__ _Float16      xs1[NBc * Lc];        // 16 KB  X_in          (f16)
    __shared__ _Float16      xo_lds[NBc * DECc];   // 512 B  cont_out * w00
    __shared__ unsigned char catb[NBc * Lc];       // 8 KB   cat_in  (CARD<256)
    __shared__ unsigned char catob[NBc * DECc];    // 256 B  cat_out
    __shared__ float         h32_lds[NBc * 132];   // 2.1 KB fp32 h for heads
    __shared__ float         wh_lds[6 * Hc];       // 3 KB   head weights
    __shared__ float         hb_lds[8];            // head biases

    const int tid  = threadIdx.x;
    const int lane = tid & 63;
    const int wv   = tid >> 6;        // wave 0..7
    const int quad = lane >> 4;       // 0..3
    const int col  = lane & 15;       // C-col (= batch)
    const int b0   = blockIdx.x * NBc;
    const float w00 = cont_w[0];

    const int xk = tid >> 2, xb = tid & 3;          // x-writer role (tid<72)
    const int cell_base = 16 * wv + quad * 4;       // cells owned: cell_base + r

    // ---------------- staging: everything into LDS once ----------------
    {
        int* z32 = (int*)&z_lds[0][0];
        for (int i = tid; i < 2 * KT * 256; i += NTc) z32[i] = 0;
    }
    for (int i = tid; i < NBc * Lc; i += NTc) {
        const int b = i >> 11, t = i & (Lc - 1);
        catb[i] = (unsigned char)cat_in[(b0 + b) * Lc + t];
        xs0[i]  = (_Float16)(cont_in[(b0 + b) * Lc + t] * w00);
        xs1[i]  = (_Float16)(X_in[(b0 + b) * Lc + t]);
    }
    if (tid < NBc * DECc) {
        const int b = tid >> 6, t = tid & 63;
        catob[tid]  = (unsigned char)cat_out[(b0 + b) * DECc + t];
        xo_lds[tid] = (_Float16)(cont_out[(b0 + b) * DECc + t] * w00);
    }
    for (int i = tid; i < CARD * EMBc; i += NTc) emb_lds[i] = (_Float16)emb_table[i];
    for (int i = tid; i < 6 * Hc; i += NTc) {
        const int o = i >> 7, k = i & 127;
        wh_lds[i] = (o == 0) ? Wm[k] : (o == 1) ? Ws[k] : Wv[(o - 2) * Hc + k];
    }
    if (tid == 0) { hb_lds[0] = bm[0]; hb_lds[1] = bs[0]; }
    if (tid < 4)  { hb_lds[2 + tid] = bv[tid]; }

    // ---- A-fragments: wave wv owns row-tiles {wv + 8i} = gate i, cells 16wv..16wv+15 ----
    half8 Af[4][KT];
    float4v bias4[4];
    #define LOAD_AB(WIH, WHH, BB)                                              \
    {                                                                          \
        _Pragma("unroll")                                                      \
        for (int i = 0; i < 4; ++i) {                                          \
            const int row = 128 * i + 16 * wv + col;                           \
            _Pragma("unroll")                                                  \
            for (int kt = 0; kt < KT; ++kt) {                                  \
                half8 f;                                                       \
                _Pragma("unroll")                                              \
                for (int j = 0; j < 8; ++j) {                                  \
                    const int k = 32 * kt + quad * 8 + j;                      \
                    float v = 0.0f;                                            \
                    if (k < INc)            v = WIH[row * INc + k];            \
                    else if (k < INc + Hc)  v = WHH[row * Hc + (k - INc)];     \
                    f[j] = (_Float16)v;                                        \
                }                                                              \
                Af[i][kt] = f;                                                 \
            }                                                                  \
            float4v bb;                                                        \
            _Pragma("unroll")                                                  \
            for (int r = 0; r < 4; ++r) bb[r] = BB[128 * i + cell_base + r];   \
            bias4[i] = bb;                                                     \
        }                                                                      \
    }

    LOAD_AB(Wih_e, Whh_e, b_e);

    __syncthreads();           // staging visible

    // x(0) into z[0] (h part already zero)
    if (tid < INc * NBc) {
        _Float16 v;
        if (xk < EMBc)       v = emb_lds[(int)catb[xb * Lc] * EMBc + xk];
        else if (xk == EMBc) v = xs0[xb * Lc];
        else                 v = xs1[xb * Lc];
        z_lds[0][zslot(xk, xb)] = v;
    }
    __syncthreads();

    _Float16* zr = &z_lds[0][0];
    _Float16* zw = &z_lds[1][0];
    float c4[4] = {0.f, 0.f, 0.f, 0.f};

    // ===================== encoder: 1 barrier/step =====================
    for (int t = 0; t < Lc; ++t) {
        const _Float16* zp = zr + lane * 8;
        half8 bf[KT];
        #pragma unroll
        for (int kt = 0; kt < KT; ++kt) bf[kt] = *(const half8*)(zp + kt * 512);

        float4v acc[4];
        #pragma unroll
        for (int i = 0; i < 4; ++i) {
            float4v a = bias4[i];
            #pragma unroll
            for (int kt = 0; kt < KT; ++kt)
                a = __builtin_amdgcn_mfma_f32_16x16x32_f16(Af[i][kt], bf[kt], a, 0, 0, 0);
            acc[i] = a;
        }

        // in-register LSTM cell update (cells cell_base+r, this lane's col)
        _Float16 hh[4];
        #pragma unroll
        for (int r = 0; r < 4; ++r) {
            const float cn = sigm(acc[1][r]) * c4[r] + sigm(acc[0][r]) * tanh_(acc[2][r]);
            c4[r] = cn;
            hh[r] = (_Float16)(sigm(acc[3][r]) * tanh_(cn));
        }

        if (col < NBc) {
            #pragma unroll
            for (int r = 0; r < 4; ++r)
                zw[zslot(INc + cell_base + r, col)] = hh[r];
        }
        // x(t+1) from LDS (clamped: t=Lc-1 writes the decoder-init x)
        if (tid < INc * NBc) {
            const int t1 = (t + 1 < Lc) ? t + 1 : Lc - 1;
            _Float16 v;
            if (xk < EMBc)       v = emb_lds[(int)catb[xb * Lc + t1] * EMBc + xk];
            else if (xk == EMBc) v = xs0[xb * Lc + t1];
            else                 v = xs1[xb * Lc + t1];
            zw[zslot(xk, xb)] = v;
        }
        __syncthreads();
        _Float16* tmp = zr; zr = zw; zw = tmp;
    }

    // ===================== decoder =====================
    LOAD_AB(Wih_d, Whh_d, b_d);
    const float bm0 = hb_lds[0], bs0 = hb_lds[1];

    for (int t = 0; t < DECc; ++t) {
        const _Float16* zp = zr + lane * 8;
        half8 bf[KT];
        #pragma unroll
        for (int kt = 0; kt < KT; ++kt) bf[kt] = *(const half8*)(zp + kt * 512);

        float4v acc[4];
        #pragma unroll
        for (int i = 0; i < 4; ++i) {
            float4v a = bias4[i];
            #pragma unroll
            for (int kt = 0; kt < KT; ++kt)
                a = __builtin_amdgcn_mfma_f32_16x16x32_f16(Af[i][kt], bf[kt], a, 0, 0, 0);
            acc[i] = a;
        }

        _Float16 hh[4];
        float h32v[4];
        #pragma unroll
        for (int r = 0; r < 4; ++r) {
            const float cn = sigm(acc[1][r]) * c4[r] + sigm(acc[0][r]) * tanh_(acc[2][r]);
            c4[r] = cn;
            const float hv = sigm(acc[3][r]) * tanh_(cn);
            h32v[r] = hv;
            hh[r] = (_Float16)hv;
        }

        if (col < NBc) {
            #pragma unroll
            for (int r = 0; r < 4; ++r) {
                zw[zslot(INc + cell_base + r, col)] = hh[r];
                h32_lds[col * 132 + cell_base + r]  = h32v[r];
            }
        }
        // feats_out(t) -> x(t+1); slot 17 (mu) written by heads below
        if (tid < INc * NBc && xk < INc - 1) {
            _Float16 v;
            if (xk < EMBc) v = emb_lds[(int)catob[xb * DECc + t] * EMBc + xk];
            else           v = xo_lds[xb * DECc + t];
            zw[zslot(xk, xb)] = v;
        }
        __syncthreads();

        // heads: mu, std, v[0..3] per batch (24 active lanes, pure LDS inputs)
        if (tid < NBc * 8) {
            const int b = tid >> 3, o = tid & 7;
            if (o < 6) {
                float s = 0.0f;
                #pragma unroll 8
                for (int k = 0; k < Hc; ++k) s += wh_lds[o * Hc + k] * h32_lds[b * 132 + k];
                const int gb = b0 + b;
                if (o == 0) {
                    const float mu = s + bm0;
                    out[gb * DECc + t] = mu;
                    zw[zslot(INc - 1, b)] = (_Float16)mu;   // mu feedback into next-step x
                } else if (o == 1) {
                    out[65536 + gb * DECc + t] = softplus_(s + bs0);
                } else {
                    out[131072 + (gb * DECc + t) * 4 + (o - 2)] = s + hb_lds[2 + (o - 2)];
                }
            }
        }
        __syncthreads();
        _Float16* tmp = zr; zr = zw; zw = tmp;
    }
    #undef LOAD_AB
}

extern "C" void kernel_launch(void* const* d_in, const int* in_sizes, int n_in,
                              void* d_out, int out_size, void* d_ws, size_t ws_size,
                              hipStream_t stream) {
    rnnar_kernel<<<1024 / NBc, NTc, 0, stream>>>(
        (const int*)d_in[0],   (const float*)d_in[1],  (const float*)d_in[2],
        (const int*)d_in[3],   (const float*)d_in[4],  (const float*)d_in[5],
        (const float*)d_in[6],
        (const float*)d_in[7], (const float*)d_in[8],  (const float*)d_in[9],
        (const float*)d_in[10],(const float*)d_in[11], (const float*)d_in[12],
        (const float*)d_in[13],(const float*)d_in[14],
        (const float*)d_in[15],(const float*)d_in[16],
        (const float*)d_in[17],(const float*)d_in[18],
        (float*)d_out);
}

// Round 9
// 1712.620 us; speedup vs baseline: 2.3743x; 2.3743x over previous
//
#include <hip/hip_runtime.h>
#include <math.h>

typedef _Float16 half8 __attribute__((ext_vector_type(8)));
typedef _Float16 half4 __attribute__((ext_vector_type(4)));
typedef float float4v __attribute__((ext_vector_type(4)));

constexpr int Lc   = 2048;  // L_IN
constexpr int DECc = 64;    // DEC_LEN
constexpr int Hc   = 128;   // H
constexpr int EMBc = 16;    // EMB
constexpr int INc  = 18;    // IN_SIZE
constexpr int NBc  = 4;     // batches per block
constexpr int NTc  = 512;   // 8 waves
constexpr int KT   = 5;     // k-tiles of 32 (z padded to 160)
constexpr int CARD = 200;
constexpr int GS2  = 528;   // g16 per-batch stride in halves (16 distinct banks for b64 writes)

__device__ __forceinline__ float rcp_(float x) { return __builtin_amdgcn_rcpf(x); }
__device__ __forceinline__ float sigm(float x) { return rcp_(1.0f + __expf(-x)); }
__device__ __forceinline__ float tanh_(float x) { return 2.0f * rcp_(1.0f + __expf(-2.0f * x)) - 1.0f; }
__device__ __forceinline__ float softplus_(float x) { return __logf(1.0f + __expf(x)); }

// z LDS layout = B-fragment order for mfma_f32_16x16x32_f16 (verified R4-R8):
// frag kt: lane l holds halves [l*8..l*8+8) = B[k = kt*32 + (l>>4)*8 + j][n = l&15]
__device__ __forceinline__ int zslot(int k, int b) {
    return (k >> 5) * 512 + (b + 16 * ((k & 31) >> 3)) * 8 + (k & 7);
}

__global__ __launch_bounds__(NTc, 1) void rnnar_kernel(
    const int*   __restrict__ cat_in,  const float* __restrict__ cont_in,
    const float* __restrict__ X_in,    const int*   __restrict__ cat_out,
    const float* __restrict__ cont_out,const float* __restrict__ emb_table,
    const float* __restrict__ cont_w,
    const float* __restrict__ Wih_e, const float* __restrict__ Whh_e, const float* __restrict__ b_e,
    const float* __restrict__ Wih_d, const float* __restrict__ Whh_d, const float* __restrict__ b_d,
    const float* __restrict__ Wm, const float* __restrict__ bm,
    const float* __restrict__ Ws, const float* __restrict__ bs,
    const float* __restrict__ Wv, const float* __restrict__ bv,
    float* __restrict__ out)
{
    // total static LDS ~62.7 KB
    __shared__ _Float16      z_lds[KT * 512];      // 5 KB   single-buffer B-frags
    __shared__ _Float16      g16[NBc * GS2];       // 4.2 KB gate pre-activations (f16, incl bias)
    __shared__ _Float16      emb_lds[CARD * EMBc]; // 6.4 KB embedding table (f16)
    __shared__ _Float16      xs0[NBc * Lc];        // 16 KB  cont_in * w00  (f16)
    __shared__ _Float16      xs1[NBc * Lc];        // 16 KB  X_in          (f16)
    __shared__ _Float16      xo_lds[NBc * DECc];   // 512 B  cont_out * w00
    __shared__ unsigned char catb[NBc * Lc];       // 8 KB   cat_in  (CARD<256)
    __shared__ unsigned char catob[NBc * DECc];    // 256 B  cat_out
    __shared__ float         h32_lds[NBc * 132];   // 2.1 KB fp32 h for heads
    __shared__ float         wh_lds[6 * Hc];       // 3 KB   head weights
    __shared__ float         hb_lds[8];            // head biases

    const int tid  = threadIdx.x;
    const int lane = tid & 63;
    const int wv   = tid >> 6;        // wave 0..7
    const int quad = lane >> 4;       // 0..3
    const int col  = lane & 15;       // C-col (= batch)
    const int b0   = blockIdx.x * NBc;
    const float w00 = cont_w[0];

    const int xk = tid >> 2, xb = tid & 3;          // x-writer role (tid<72)
    const int m = tid & (Hc - 1), pb = tid >> 7;    // phase-2 role (tid<512)
    const int cell_base = 16 * wv + quad * 4;

    // ---------------- staging: everything into LDS once ----------------
    {
        int* z32 = (int*)z_lds;
        for (int i = tid; i < KT * 256; i += NTc) z32[i] = 0;
    }
    for (int i = tid; i < NBc * Lc; i += NTc) {
        const int b = i >> 11, t = i & (Lc - 1);
        catb[i] = (unsigned char)cat_in[(b0 + b) * Lc + t];
        xs0[i]  = (_Float16)(cont_in[(b0 + b) * Lc + t] * w00);
        xs1[i]  = (_Float16)(X_in[(b0 + b) * Lc + t]);
    }
    if (tid < NBc * DECc) {
        const int b = tid >> 6, t = tid & 63;
        catob[tid]  = (unsigned char)cat_out[(b0 + b) * DECc + t];
        xo_lds[tid] = (_Float16)(cont_out[(b0 + b) * DECc + t] * w00);
    }
    for (int i = tid; i < CARD * EMBc; i += NTc) emb_lds[i] = (_Float16)emb_table[i];
    for (int i = tid; i < 6 * Hc; i += NTc) {
        const int o = i >> 7, k = i & 127;
        wh_lds[i] = (o == 0) ? Wm[k] : (o == 1) ? Ws[k] : Wv[(o - 2) * Hc + k];
    }
    if (tid == 0) { hb_lds[0] = bm[0]; hb_lds[1] = bs[0]; }
    if (tid < 4)  { hb_lds[2 + tid] = bv[tid]; }

    // ---- A-fragments: wave wv owns row-tiles {wv + 8i} = gate i, cells 16wv..16wv+15 ----
    half8 Af[4][KT];
    float4v bias4[4];
    #define LOAD_AB(WIH, WHH, BB)                                              \
    {                                                                          \
        _Pragma("unroll")                                                      \
        for (int i = 0; i < 4; ++i) {                                          \
            const int row = 128 * i + 16 * wv + col;                           \
            _Pragma("unroll")                                                  \
            for (int kt = 0; kt < KT; ++kt) {                                  \
                half8 f;                                                       \
                _Pragma("unroll")                                              \
                for (int j = 0; j < 8; ++j) {                                  \
                    const int k = 32 * kt + quad * 8 + j;                      \
                    float v = 0.0f;                                            \
                    if (k < INc)            v = WIH[row * INc + k];            \
                    else if (k < INc + Hc)  v = WHH[row * Hc + (k - INc)];     \
                    f[j] = (_Float16)v;                                        \
                }                                                              \
                Af[i][kt] = f;                                                 \
            }                                                                  \
            float4v bb;                                                        \
            _Pragma("unroll")                                                  \
            for (int r = 0; r < 4; ++r) bb[r] = BB[128 * i + cell_base + r];   \
            bias4[i] = bb;                                                     \
        }                                                                      \
    }

    LOAD_AB(Wih_e, Whh_e, b_e);

    __syncthreads();   // staging visible

    // x(0) into z (h part already zero)
    if (tid < INc * NBc) {
        _Float16 v;
        if (xk < EMBc)       v = emb_lds[(int)catb[xb * Lc] * EMBc + xk];
        else if (xk == EMBc) v = xs0[xb * Lc];
        else                 v = xs1[xb * Lc];
        z_lds[zslot(xk, xb)] = v;
    }
    __syncthreads();

    float c_reg = 0.f;
    const _Float16* zp = z_lds + lane * 8;

    // ===================== encoder =====================
    for (int t = 0; t < Lc; ++t) {
        // phase 1: MFMA gates, result -> g16 (f16)
        half8 bf[KT];
        #pragma unroll
        for (int kt = 0; kt < KT; ++kt) bf[kt] = *(const half8*)(zp + kt * 512);
        #pragma unroll
        for (int i = 0; i < 4; ++i) {
            float4v a = bias4[i];
            #pragma unroll
            for (int kt = 0; kt < KT; ++kt)
                a = __builtin_amdgcn_mfma_f32_16x16x32_f16(Af[i][kt], bf[kt], a, 0, 0, 0);
            if (col < NBc) {
                half4 hv;
                #pragma unroll
                for (int r = 0; r < 4; ++r) hv[r] = (_Float16)a[r];
                *(half4*)(g16 + col * GS2 + 128 * i + cell_base) = hv;
            }
        }
        __syncthreads();

        // phase 2: one cell-update per thread (cell m, batch pb) — all-LDS inputs
        {
            const float gi = (float)g16[pb * GS2 + m];
            const float gf = (float)g16[pb * GS2 + 128 + m];
            const float gg = (float)g16[pb * GS2 + 256 + m];
            const float go = (float)g16[pb * GS2 + 384 + m];
            const float cn = sigm(gf) * c_reg + sigm(gi) * tanh_(gg);
            c_reg = cn;
            z_lds[zslot(INc + m, pb)] = (_Float16)(sigm(go) * tanh_(cn));
        }
        // x(t+1) from LDS (clamped: t=Lc-1 re-writes x(Lc-1) = decoder-init x)
        if (tid < INc * NBc) {
            const int t1 = (t + 1 < Lc) ? t + 1 : Lc - 1;
            _Float16 v;
            if (xk < EMBc)       v = emb_lds[(int)catb[xb * Lc + t1] * EMBc + xk];
            else if (xk == EMBc) v = xs0[xb * Lc + t1];
            else                 v = xs1[xb * Lc + t1];
            z_lds[zslot(xk, xb)] = v;
        }
        __syncthreads();
    }

    // ===================== decoder =====================
    LOAD_AB(Wih_d, Whh_d, b_d);
    const float bm0 = hb_lds[0], bs0 = hb_lds[1];

    for (int t = 0; t < DECc; ++t) {
        half8 bf[KT];
        #pragma unroll
        for (int kt = 0; kt < KT; ++kt) bf[kt] = *(const half8*)(zp + kt * 512);
        #pragma unroll
        for (int i = 0; i < 4; ++i) {
            float4v a = bias4[i];
            #pragma unroll
            for (int kt = 0; kt < KT; ++kt)
                a = __builtin_amdgcn_mfma_f32_16x16x32_f16(Af[i][kt], bf[kt], a, 0, 0, 0);
            if (col < NBc) {
                half4 hv;
                #pragma unroll
                for (int r = 0; r < 4; ++r) hv[r] = (_Float16)a[r];
                *(half4*)(g16 + col * GS2 + 128 * i + cell_base) = hv;
            }
        }
        __syncthreads();

        // phase 2
        {
            const float gi = (float)g16[pb * GS2 + m];
            const float gf = (float)g16[pb * GS2 + 128 + m];
            const float gg = (float)g16[pb * GS2 + 256 + m];
            const float go = (float)g16[pb * GS2 + 384 + m];
            const float cn = sigm(gf) * c_reg + sigm(gi) * tanh_(gg);
            c_reg = cn;
            const float hv = sigm(go) * tanh_(cn);
            z_lds[zslot(INc + m, pb)] = (_Float16)hv;
            h32_lds[pb * 132 + m] = hv;
        }
        // feats_out(t) -> x(t+1); slot 17 (mu) written by heads below
        if (tid < INc * NBc && xk < INc - 1) {
            _Float16 v;
            if (xk < EMBc) v = emb_lds[(int)catob[xb * DECc + t] * EMBc + xk];
            else           v = xo_lds[xb * DECc + t];
            z_lds[zslot(xk, xb)] = v;
        }
        __syncthreads();

        // phase 3: heads (mu, std, v[0..3]) per batch — pure LDS inputs
        if (tid < NBc * 8) {
            const int b = tid >> 3, o = tid & 7;
            if (o < 6) {
                float s = 0.0f;
                #pragma unroll 8
                for (int k = 0; k < Hc; ++k) s += wh_lds[o * Hc + k] * h32_lds[b * 132 + k];
                const int gb = b0 + b;
                if (o == 0) {
                    const float mu = s + bm0;
                    out[gb * DECc + t] = mu;
                    z_lds[zslot(INc - 1, b)] = (_Float16)mu;   // mu feedback
                } else if (o == 1) {
                    out[65536 + gb * DECc + t] = softplus_(s + bs0);
                } else {
                    out[131072 + (gb * DECc + t) * 4 + (o - 2)] = s + hb_lds[2 + (o - 2)];
                }
            }
        }
        __syncthreads();
    }
    #undef LOAD_AB
}

extern "C" void kernel_launch(void* const* d_in, const int* in_sizes, int n_in,
                              void* d_out, int out_size, void* d_ws, size_t ws_size,
                              hipStream_t stream) {
    rnnar_kernel<<<1024 / NBc, NTc, 0, stream>>>(
        (const int*)d_in[0],   (const float*)d_in[1],  (const float*)d_in[2],
        (const int*)d_in[3],   (const float*)d_in[4],  (const float*)d_in[5],
        (const float*)d_in[6],
        (const float*)d_in[7], (const float*)d_in[8],  (const float*)d_in[9],
        (const float*)d_in[10],(const float*)d_in[11], (const float*)d_in[12],
        (const float*)d_in[13],(const float*)d_in[14],
        (const float*)d_in[15],(const float*)d_in[16],
        (const float*)d_in[17],(const float*)d_in[18],
        (float*)d_out);
}